// Round 21
// baseline (256.187 us; speedup 1.0000x reference)
//
#include <hip/hip_runtime.h>

#define K_DIM 512
#define S_DIM 64
#define T_LEN 64
#define BW    16      // sequences per workgroup
#define NWG   32      // 32 workgroups x 16 seqs = 512

typedef float f32x4 __attribute__((ext_vector_type(4)));
typedef float f32x2 __attribute__((ext_vector_type(2)));
typedef long  i64x2 __attribute__((ext_vector_type(2)));

__device__ __forceinline__ char f2fp8(float f) {   // OCP e4m3 on gfx950
    return (char)__builtin_amdgcn_cvt_pk_fp8_f32(f, f, 0, false);
}

// ---------------- pre-pass: fp8 A + fp8 Ceff + packed {pi, pi*Bt} ----------------
__global__ void ssm_prep(const float* __restrict__ A, const float* __restrict__ B,
                         const float* __restrict__ C, const float* __restrict__ Pp,
                         char* __restrict__ A8, char* __restrict__ C8,
                         f32x2* __restrict__ PPB) {
    int i = blockIdx.x * blockDim.x + threadIdx.x;
    int stride = gridDim.x * blockDim.x;
    for (int idx = i; idx < K_DIM * K_DIM; idx += stride)
        A8[idx] = f2fp8(A[idx]);
    for (int idx = i; idx < S_DIM * K_DIM; idx += stride) {
        int s = idx >> 9;               // K_DIM == 512
        int k = idx & (K_DIM - 1);
        float p = 1.0f / (1.0f + expf(-Pp[idx]));
        C8[idx] = f2fp8(C[idx] * p);
        PPB[idx] = (f32x2){p, p * B[k * S_DIM + s]};   // {pi, pi*Bt[tok][k]}
    }
}

#define MFMA8(xj, aj, acc) acc = __builtin_amdgcn_mfma_f32_16x16x32_fp8_fp8(xj, aj, acc, 0, 0, 0)

// stream macro-slice m (K=64 chunk): 4 nt-rows x dwordx4 (16 fp8 = 2 k-slices)
#define LOADM(m) \
    i64x2 ga_##m = *(const i64x2*)(a8P0 + (m) * 64); \
    i64x2 gb_##m = *(const i64x2*)(a8P1 + (m) * 64); \
    i64x2 gc_##m = *(const i64x2*)(a8P2 + (m) * 64); \
    i64x2 gd_##m = *(const i64x2*)(a8P3 + (m) * 64);

// consume macro m from block-scope stream temps
#define COMPM(m) { \
    i64x2 xv = *(const i64x2*)&Xb8[lr][(m) * 64 + 16 * lg]; \
    MFMA8(xv[0], ga_##m[0], acc0); MFMA8(xv[1], ga_##m[1], acc0); \
    MFMA8(xv[0], gb_##m[0], acc1); MFMA8(xv[1], gb_##m[1], acc1); \
    MFMA8(xv[0], gc_##m[0], acc2); MFMA8(xv[1], gc_##m[1], acc2); \
    MFMA8(xv[0], gd_##m[0], acc3); MFMA8(xv[1], gd_##m[1], acc3); }

// consume macro m from loop-carried fragments (landed across the barrier)
#define COMPC(pa, pb, pc, pd, m) { \
    i64x2 xv = *(const i64x2*)&Xb8[lr][(m) * 64 + 16 * lg]; \
    MFMA8(xv[0], pa[0], acc0); MFMA8(xv[1], pa[1], acc0); \
    MFMA8(xv[0], pb[0], acc1); MFMA8(xv[1], pb[1], acc1); \
    MFMA8(xv[0], pc[0], acc2); MFMA8(xv[1], pc[1], acc2); \
    MFMA8(xv[0], pd[0], acc3); MFMA8(xv[1], pd[1], acc3); }

// consume LDS-resident macro m (4..7): lane l's 16B at Aq8[w][m-4][nt][l]
#define COMPML(m) { \
    i64x2 xv = *(const i64x2*)&Xb8[lr][(m) * 64 + 16 * lg]; \
    i64x2 f0 = *(const i64x2*)&Aq8[w][(m) - 4][0][l][0]; \
    i64x2 f1 = *(const i64x2*)&Aq8[w][(m) - 4][1][l][0]; \
    i64x2 f2 = *(const i64x2*)&Aq8[w][(m) - 4][2][l][0]; \
    i64x2 f3 = *(const i64x2*)&Aq8[w][(m) - 4][3][l][0]; \
    MFMA8(xv[0], f0[0], acc0); MFMA8(xv[1], f0[1], acc0); \
    MFMA8(xv[0], f1[0], acc1); MFMA8(xv[1], f1[1], acc1); \
    MFMA8(xv[0], f2[0], acc2); MFMA8(xv[1], f2[1], acc2); \
    MFMA8(xv[0], f3[0], acc3); MFMA8(xv[1], f3[1], acc3); }

// reload loop-carried operands: 4 Ceff frags + stream macros 0,1 (14 loads,
// step-invariant addresses). Issued at end of P3 -> latency drains under
// softmax + barrier2; consumed next step in P1 / COMPC with zero stall.
#define CARRY() do { \
    cv0 = *(const i64x2*)(c8P);        cv1 = *(const i64x2*)(c8P +  64); \
    cv2 = *(const i64x2*)(c8P + 128);  cv3 = *(const i64x2*)(c8P + 192); \
    p0a = *(const i64x2*)(a8P0);       p0b = *(const i64x2*)(a8P1); \
    p0c = *(const i64x2*)(a8P2);       p0d = *(const i64x2*)(a8P3); \
    p1a = *(const i64x2*)(a8P0 + 64);  p1b = *(const i64x2*)(a8P1 + 64); \
    p1c = *(const i64x2*)(a8P2 + 64);  p1d = *(const i64x2*)(a8P3 + 64); \
} while (0)

// raw barrier: drain LDS ops only; wave-private vmem loads ride across
#define LBAR asm volatile("s_waitcnt lgkmcnt(0)\ns_barrier" ::: "memory")

// ---------------- main: 32 WGs x 512 threads (8 waves), 16 seqs/WG, 64 steps ----------------
// R20 + stall elimination via loop-carrying (affordable since fp8 halved all
// fragments): cv + macros 0,1 carried across barrier2 (P1 entry & COMPM(0,1)
// stalls -> 0); LOADM(2,3) at step top (covered by P1); 8-wave softmax
// (halves the tail; no wave 4-7 idle bubble).
__global__ __launch_bounds__(512) __attribute__((amdgpu_waves_per_eu(2, 2)))
void ssm_main(
    const char*  __restrict__ A8,      // [K][K] fp8 e4m3 row-major
    const char*  __restrict__ C8,      // [S][K] fp8 e4m3 (C * sigmoid(pi))
    const f32x2* __restrict__ PPB,     // [S][K] {pi, pi*Bt}
    const float* __restrict__ init,    // [K]
    const int*   __restrict__ tokens,  // [BSZ][T]
    float*       __restrict__ out)     // [BSZ]
{
    __shared__ char  Aq8[8][4][4][64][16];  // 128 KB: A cols 256..512 fp8, fragment order
    __shared__ char  Xb8[BW][528];          //  8.4 KB fp8 state (both GEMM paths)
    __shared__ float Lg[2][BW][68];         //  8.7 KB logits partials (2 K-halves)
    __shared__ int   tokS[BW][T_LEN];       //  4.1 KB   (total ~149 KB -> 1 WG/CU)

    const int tid = threadIdx.x;
    const int w  = tid >> 6;     // wave 0..7, owns k-range [w*64, w*64+64)
    const int l  = tid & 63;
    const int lg = l >> 4;
    const int lr = l & 15;
    const int b0 = blockIdx.x * BW;

    for (int idx = tid; idx < BW * T_LEN; idx += 512) {
        int r = idx >> 6, t = idx & 63;
        tokS[r][t] = tokens[(b0 + r) * T_LEN + t];
    }
    for (int idx = tid; idx < BW * K_DIM; idx += 512) {
        int r = idx >> 9, k = idx & (K_DIM - 1);
        Xb8[r][k] = f2fp8(init[k]);
    }
    // stage A fp8 macros 4..7 into LDS in fragment order (once; reused 64 steps)
    for (int idx = tid; idx < 8192; idx += 512) {
        int w2 = idx >> 10, rem = idx & 1023;
        int m2 = rem >> 8, rem2 = rem & 255;
        int q2 = rem2 >> 6, l2 = rem2 & 63;
        *(i64x2*)&Aq8[w2][m2][q2][l2][0] =
            *(const i64x2*)(A8 + (w2 * 64 + q2 * 16 + (l2 & 15)) * K_DIM
                            + (4 + m2) * 64 + (l2 >> 4) * 16);
    }
    // fp32 master state: xm[nt][e] = x[seq=4*lg+e][k = w*64 + nt*16 + lr]
    float xm[4][4];
    #pragma unroll
    for (int nt = 0; nt < 4; ++nt) {
        float iv = init[w * 64 + nt * 16 + lr];
        #pragma unroll
        for (int e = 0; e < 4; ++e) xm[nt][e] = iv;
    }

    const int sq = w & 3;    // logits s-tile
    const int kh = w >> 2;   // logits K-half

    // per-lane fp8 A bases (one per nt-quarter of the wave's 64 rows)
    const char* a8P0 = A8 + (w * 64 +      lr) * K_DIM + 16 * lg;
    const char* a8P1 = A8 + (w * 64 + 16 + lr) * K_DIM + 16 * lg;
    const char* a8P2 = A8 + (w * 64 + 32 + lr) * K_DIM + 16 * lg;
    const char* a8P3 = A8 + (w * 64 + 48 + lr) * K_DIM + 16 * lg;
    const char* c8P  = C8 + (sq * 16 + lr) * K_DIM + kh * 256 + 16 * lg;

    // loop-carried operands (48 VGPRs): Ceff frags + stream macros 0,1
    i64x2 cv0, cv1, cv2, cv3;
    i64x2 p0a, p0b, p0c, p0d, p1a, p1b, p1c, p1d;
    CARRY();

    float llacc = 0.0f;
    __syncthreads();

    for (int t = 0; t < T_LEN; ++t) {
        // ---- issue macros 2,3 now; they land during P1 + COMPC(0,1)
        LOADM(2) LOADM(3)

        // ---- P1: logits partial GEMM (K-half kh), fp8; cv carried (zero stall)
        f32x4 lga = {0.f, 0.f, 0.f, 0.f};
        {
            i64x2 xv0 = *(const i64x2*)&Xb8[lr][kh * 256 +   0 + 16 * lg];
            MFMA8(xv0[0], cv0[0], lga); MFMA8(xv0[1], cv0[1], lga);
            i64x2 xv1 = *(const i64x2*)&Xb8[lr][kh * 256 +  64 + 16 * lg];
            MFMA8(xv1[0], cv1[0], lga); MFMA8(xv1[1], cv1[1], lga);
            i64x2 xv2 = *(const i64x2*)&Xb8[lr][kh * 256 + 128 + 16 * lg];
            MFMA8(xv2[0], cv2[0], lga); MFMA8(xv2[1], cv2[1], lga);
            i64x2 xv3 = *(const i64x2*)&Xb8[lr][kh * 256 + 192 + 16 * lg];
            MFMA8(xv3[0], cv3[0], lga); MFMA8(xv3[1], cv3[1], lga);
        }
        #pragma unroll
        for (int e = 0; e < 4; ++e)
            Lg[kh][4 * lg + e][sq * 16 + lr] = lga[e];

        // ---- P2: macros 0,1 carried (clean); 2,3 landed during P1; 4..7 LDS
        f32x4 acc0 = {0.f, 0.f, 0.f, 0.f};
        f32x4 acc1 = {0.f, 0.f, 0.f, 0.f};
        f32x4 acc2 = {0.f, 0.f, 0.f, 0.f};
        f32x4 acc3 = {0.f, 0.f, 0.f, 0.f};
        COMPC(p0a, p0b, p0c, p0d, 0)
        COMPC(p1a, p1b, p1c, p1d, 1)
        COMPM(2)
        COMPM(3)
        // ---- gating gathers: zero A-loads in flight; latency hides under LDS tail
        int mytok[4];
        #pragma unroll
        for (int e = 0; e < 4; ++e) mytok[e] = tokS[4 * lg + e][t];
        f32x2 ppv[4][4];
        #pragma unroll
        for (int nt = 0; nt < 4; ++nt) {
            int k = w * 64 + nt * 16 + lr;
            #pragma unroll
            for (int e = 0; e < 4; ++e)
                ppv[nt][e] = PPB[mytok[e] * K_DIM + k];
        }
        // ---- macros 4..7 from LDS (zero vmem)
        COMPML(4) COMPML(5) COMPML(6) COMPML(7)
        LBAR;   // barrier1: Xb8 reads done, Lg visible

        // ---- P3: gating in fp32, rewrite Xb8 (fp8 only)
        #pragma unroll
        for (int nt = 0; nt < 4; ++nt) {
            int k = w * 64 + nt * 16 + lr;
            #pragma unroll
            for (int e = 0; e < 4; ++e) {
                float a  = (nt == 0) ? acc0[e] : (nt == 1) ? acc1[e]
                         : (nt == 2) ? acc2[e] : acc3[e];
                float nx = xm[nt][e] + ppv[nt][e][0] * (a - xm[nt][e]) + ppv[nt][e][1];
                xm[nt][e] = nx;
                Xb8[4 * lg + e][k] = f2fp8(nx);
            }
        }
        // ---- reload carried operands for next step; drains under softmax+barrier
        CARRY();
        // ---- softmax across ALL 8 waves: 2 seqs/wave, 32 lanes/seq, 2 logits/lane
        {
            int b = w * 2 + (l >> 5);
            int i = l & 31;
            float v0 = Lg[0][b][i * 2]     + Lg[1][b][i * 2];
            float v1 = Lg[0][b][i * 2 + 1] + Lg[1][b][i * 2 + 1];
            float m = fmaxf(v0, v1);
            m = fmaxf(m, __shfl_xor(m, 1));
            m = fmaxf(m, __shfl_xor(m, 2));
            m = fmaxf(m, __shfl_xor(m, 4));
            m = fmaxf(m, __shfl_xor(m, 8));
            m = fmaxf(m, __shfl_xor(m, 16));
            float sum = expf(v0 - m) + expf(v1 - m);
            sum += __shfl_xor(sum, 1);
            sum += __shfl_xor(sum, 2);
            sum += __shfl_xor(sum, 4);
            sum += __shfl_xor(sum, 8);
            sum += __shfl_xor(sum, 16);
            int tok = tokS[b][t];
            float sel = (i == (tok >> 1)) ? ((tok & 1) ? v1 : v0) : 0.0f;
            sel += __shfl_xor(sel, 1);
            sel += __shfl_xor(sel, 2);
            sel += __shfl_xor(sel, 4);
            sel += __shfl_xor(sel, 8);
            sel += __shfl_xor(sel, 16);
            llacc += sel - m - logf(sum);
        }
        LBAR;   // barrier2: new Xb8 visible, Lg consumed
    }

    if ((l & 31) == 0)
        out[b0 + w * 2 + (l >> 5)] = llacc;
}

extern "C" void kernel_launch(void* const* d_in, const int* in_sizes, int n_in,
                              void* d_out, int out_size, void* d_ws, size_t ws_size,
                              hipStream_t stream) {
    const float* A  = (const float*)d_in[0];   // (512,512)
    const float* B  = (const float*)d_in[1];   // (512,64)
    const float* C  = (const float*)d_in[2];   // (64,512)
    const float* Pp = (const float*)d_in[3];   // (64,512)
    const float* init = (const float*)d_in[4]; // (512,)
    const int* tokens = (const int*)d_in[5];   // (512,64)
    float* out = (float*)d_out;

    // workspace layout (needs 557,056 bytes)
    char*  A8  = (char*)d_ws;                                  // 512*512*1 = 262144
    char*  C8  = (char*)d_ws + 262144;                         // 64*512*1  =  32768
    f32x2* PPB = (f32x2*)((char*)d_ws + 294912);               // 64*512*8  = 262144

    ssm_prep<<<256, 256, 0, stream>>>(A, B, C, Pp, A8, C8, PPB);
    ssm_main<<<NWG, 512, 0, stream>>>(A8, C8, PPB, init, tokens, out);
}

// Round 22
// 177.617 us; speedup vs baseline: 1.4424x; 1.4424x over previous
//
#include <hip/hip_runtime.h>

#define K_DIM 512
#define S_DIM 64
#define T_LEN 64
#define BW    16      // sequences per workgroup
#define NWG   32      // 32 workgroups x 16 seqs = 512

typedef float f32x4 __attribute__((ext_vector_type(4)));
typedef float f32x2 __attribute__((ext_vector_type(2)));
typedef long  i64x2 __attribute__((ext_vector_type(2)));

__device__ __forceinline__ char f2fp8(float f) {   // OCP e4m3 on gfx950
    return (char)__builtin_amdgcn_cvt_pk_fp8_f32(f, f, 0, false);
}
// pack 4 floats -> 4 fp8 bytes (little-endian: a=byte0 .. d=byte3)
__device__ __forceinline__ unsigned pack4fp8(float a, float b, float c, float d) {
    unsigned v = __builtin_amdgcn_cvt_pk_fp8_f32(a, b, 0, false);
    v = __builtin_amdgcn_cvt_pk_fp8_f32(c, d, v, true);
    return v;
}

// ---------------- pre-pass: fp8 A + fp8 Ceff + packed {pi, pi*Bt} ----------------
__global__ void ssm_prep(const float* __restrict__ A, const float* __restrict__ B,
                         const float* __restrict__ C, const float* __restrict__ Pp,
                         char* __restrict__ A8, char* __restrict__ C8,
                         f32x2* __restrict__ PPB) {
    int i = blockIdx.x * blockDim.x + threadIdx.x;
    int stride = gridDim.x * blockDim.x;
    for (int idx = i; idx < K_DIM * K_DIM; idx += stride)
        A8[idx] = f2fp8(A[idx]);
    for (int idx = i; idx < S_DIM * K_DIM; idx += stride) {
        int s = idx >> 9;               // K_DIM == 512
        int k = idx & (K_DIM - 1);
        float p = 1.0f / (1.0f + expf(-Pp[idx]));
        C8[idx] = f2fp8(C[idx] * p);
        PPB[idx] = (f32x2){p, p * B[k * S_DIM + s]};   // {pi, pi*Bt[tok][k]}
    }
}

#define MFMA8(aj, bj, acc) acc = __builtin_amdgcn_mfma_f32_16x16x32_fp8_fp8(aj, bj, acc, 0, 0, 0)

// stream macro-slice m (K=64 chunk): 4 nt-rows x dwordx4 (16 fp8 = 2 k-slices)
#define LOADM(m) \
    i64x2 ga_##m = *(const i64x2*)(a8P0 + (m) * 64); \
    i64x2 gb_##m = *(const i64x2*)(a8P1 + (m) * 64); \
    i64x2 gc_##m = *(const i64x2*)(a8P2 + (m) * 64); \
    i64x2 gd_##m = *(const i64x2*)(a8P3 + (m) * 64);

// consume macro m: SWAPPED operand order (A-matrix = A-operand, x = B-operand)
// -> D[row=4lg+e -> k_out][col=lr -> seq]: thread owns seq=lr, 4 consecutive k
#define COMPM(m) { \
    i64x2 xv = *(const i64x2*)&Xb8[lr][(m) * 64 + 16 * lg]; \
    MFMA8(ga_##m[0], xv[0], acc0); MFMA8(ga_##m[1], xv[1], acc0); \
    MFMA8(gb_##m[0], xv[0], acc1); MFMA8(gb_##m[1], xv[1], acc1); \
    MFMA8(gc_##m[0], xv[0], acc2); MFMA8(gc_##m[1], xv[1], acc2); \
    MFMA8(gd_##m[0], xv[0], acc3); MFMA8(gd_##m[1], xv[1], acc3); }

// consume LDS-resident macro m (4..7), swapped order
#define COMPML(m) { \
    i64x2 xv = *(const i64x2*)&Xb8[lr][(m) * 64 + 16 * lg]; \
    i64x2 f0 = *(const i64x2*)&Aq8[w][(m) - 4][0][l][0]; \
    i64x2 f1 = *(const i64x2*)&Aq8[w][(m) - 4][1][l][0]; \
    i64x2 f2 = *(const i64x2*)&Aq8[w][(m) - 4][2][l][0]; \
    i64x2 f3 = *(const i64x2*)&Aq8[w][(m) - 4][3][l][0]; \
    MFMA8(f0[0], xv[0], acc0); MFMA8(f0[1], xv[1], acc0); \
    MFMA8(f1[0], xv[0], acc1); MFMA8(f1[1], xv[1], acc1); \
    MFMA8(f2[0], xv[0], acc2); MFMA8(f2[1], xv[1], acc2); \
    MFMA8(f3[0], xv[0], acc3); MFMA8(f3[1], xv[1], acc3); }

// raw barrier: drain LDS ops only; wave-private vmem loads ride across
#define LBAR asm volatile("s_waitcnt lgkmcnt(0)\ns_barrier" ::: "memory")

// ---------------- main: 32 WGs x 512 threads (8 waves), 16 seqs/WG, 64 steps ----------------
// R20 with P2 operand order swapped. Fragments are IDENTICAL; only the output
// interpretation transposes: thread (lr,lg) now owns update[k=w*64+nt*16+4lg+e]
// [seq=lr] -> 4 consecutive k per nt. Gating becomes: 1 token/thread, 8 f32x4
// ppv vector loads (was 16 scalar), 8 cvt_pk (was 16), 4 ds_write_b32 (was 16
// ds_write_b8). P1, softmax, schedule, barriers byte-identical to R20.
__global__ __launch_bounds__(512) __attribute__((amdgpu_waves_per_eu(2, 2)))
void ssm_main(
    const char*  __restrict__ A8,      // [K][K] fp8 e4m3 row-major
    const char*  __restrict__ C8,      // [S][K] fp8 e4m3 (C * sigmoid(pi))
    const f32x2* __restrict__ PPB,     // [S][K] {pi, pi*Bt}
    const float* __restrict__ init,    // [K]
    const int*   __restrict__ tokens,  // [BSZ][T]
    float*       __restrict__ out)     // [BSZ]
{
    __shared__ char  Aq8[8][4][4][64][16];  // 128 KB: A cols 256..512 fp8, fragment order
    __shared__ char  Xb8[BW][528];          //  8.4 KB fp8 state (both GEMM paths)
    __shared__ float Lg[2][BW][68];         //  8.7 KB logits partials (2 K-halves)
    __shared__ int   tokS[BW][T_LEN];       //  4.1 KB   (total ~149 KB -> 1 WG/CU)

    const int tid = threadIdx.x;
    const int w  = tid >> 6;     // wave 0..7, owns k-range [w*64, w*64+64)
    const int l  = tid & 63;
    const int lg = l >> 4;
    const int lr = l & 15;
    const int b0 = blockIdx.x * BW;

    for (int idx = tid; idx < BW * T_LEN; idx += 512) {
        int r = idx >> 6, t = idx & 63;
        tokS[r][t] = tokens[(b0 + r) * T_LEN + t];
    }
    for (int idx = tid; idx < BW * K_DIM; idx += 512) {
        int r = idx >> 9, k = idx & (K_DIM - 1);
        Xb8[r][k] = f2fp8(init[k]);
    }
    // stage A fp8 macros 4..7 into LDS in fragment order (once; reused 64 steps)
    for (int idx = tid; idx < 8192; idx += 512) {
        int w2 = idx >> 10, rem = idx & 1023;
        int m2 = rem >> 8, rem2 = rem & 255;
        int q2 = rem2 >> 6, l2 = rem2 & 63;
        *(i64x2*)&Aq8[w2][m2][q2][l2][0] =
            *(const i64x2*)(A8 + (w2 * 64 + q2 * 16 + (l2 & 15)) * K_DIM
                            + (4 + m2) * 64 + (l2 >> 4) * 16);
    }
    // fp32 master state (NEW mapping): xm[nt][e] = x[seq=lr][k = w*64+nt*16+4*lg+e]
    float xm[4][4];
    #pragma unroll
    for (int nt = 0; nt < 4; ++nt) {
        #pragma unroll
        for (int e = 0; e < 4; ++e)
            xm[nt][e] = init[w * 64 + nt * 16 + 4 * lg + e];
    }

    const int sq = w & 3;    // logits s-tile
    const int kh = w >> 2;   // logits K-half

    // per-lane fp8 A bases (one per nt-quarter of the wave's 64 rows)
    const char* a8P0 = A8 + (w * 64 +      lr) * K_DIM + 16 * lg;
    const char* a8P1 = A8 + (w * 64 + 16 + lr) * K_DIM + 16 * lg;
    const char* a8P2 = A8 + (w * 64 + 32 + lr) * K_DIM + 16 * lg;
    const char* a8P3 = A8 + (w * 64 + 48 + lr) * K_DIM + 16 * lg;
    const char* c8P  = C8 + (sq * 16 + lr) * K_DIM + kh * 256 + 16 * lg;

    float llacc = 0.0f;
    __syncthreads();

    for (int t = 0; t < T_LEN; ++t) {
        // ---- prime 2 macro-slices; latency hides under P1
        LOADM(0) LOADM(1)

        // ---- P1: logits partial GEMM (K-half kh), fp8, UNSWAPPED (x = A-op):
        //      D[seq=4lg+e][s=lr] -> Lg writes unchanged
        f32x4 lga = {0.f, 0.f, 0.f, 0.f};
        #pragma unroll
        for (int j = 0; j < 4; ++j) {
            i64x2 cv = *(const i64x2*)(c8P + j * 64);
            i64x2 xv = *(const i64x2*)&Xb8[lr][kh * 256 + j * 64 + 16 * lg];
            MFMA8(xv[0], cv[0], lga);
            MFMA8(xv[1], cv[1], lga);
        }
        #pragma unroll
        for (int e = 0; e < 4; ++e)
            Lg[kh][4 * lg + e][sq * 16 + lr] = lga[e];

        // ---- P2: update GEMM fp8 (swapped), macros 0..3 streamed depth-2
        f32x4 acc0 = {0.f, 0.f, 0.f, 0.f};
        f32x4 acc1 = {0.f, 0.f, 0.f, 0.f};
        f32x4 acc2 = {0.f, 0.f, 0.f, 0.f};
        f32x4 acc3 = {0.f, 0.f, 0.f, 0.f};
        COMPM(0)  LOADM(2)
        COMPM(1)  LOADM(3)
        COMPM(2)
        COMPM(3)
        // ---- gating gathers: 1 token/thread, 8 contiguous f32x4 loads
        int mytok = tokS[lr][t];
        f32x4 ppv[4][2];   // ppv[nt][h]: {pi(e),pb(e),pi(e+1),pb(e+1)}, e=2h
        #pragma unroll
        for (int nt = 0; nt < 4; ++nt) {
            const f32x2* pp = PPB + mytok * K_DIM + w * 64 + nt * 16 + 4 * lg;
            ppv[nt][0] = *(const f32x4*)(pp);
            ppv[nt][1] = *(const f32x4*)(pp + 2);
        }
        // ---- macros 4..7 from LDS (zero vmem)
        COMPML(4) COMPML(5) COMPML(6) COMPML(7)
        LBAR;   // barrier1: Xb8 reads done, Lg visible

        // ---- P3: gating in fp32; thread owns seq=lr, 4 consecutive k per nt
        //      -> pack 4 fp8 and ONE ds_write_b32 per nt
        #pragma unroll
        for (int nt = 0; nt < 4; ++nt) {
            f32x4 a = (nt == 0) ? acc0 : (nt == 1) ? acc1 : (nt == 2) ? acc2 : acc3;
            float nx0 = xm[nt][0] + ppv[nt][0][0] * (a[0] - xm[nt][0]) + ppv[nt][0][1];
            float nx1 = xm[nt][1] + ppv[nt][0][2] * (a[1] - xm[nt][1]) + ppv[nt][0][3];
            float nx2 = xm[nt][2] + ppv[nt][1][0] * (a[2] - xm[nt][2]) + ppv[nt][1][1];
            float nx3 = xm[nt][3] + ppv[nt][1][2] * (a[3] - xm[nt][3]) + ppv[nt][1][3];
            xm[nt][0] = nx0; xm[nt][1] = nx1; xm[nt][2] = nx2; xm[nt][3] = nx3;
            *(unsigned*)&Xb8[lr][w * 64 + nt * 16 + 4 * lg] = pack4fp8(nx0, nx1, nx2, nx3);
        }
        // waves 0..3: log-softmax + LL for 4 seqs each (16 lanes/seq, 4 logits/lane)
        if (w < 4) {
            int b = w * 4 + (l >> 4);
            int i = l & 15;
            float v[4];
            #pragma unroll
            for (int c = 0; c < 4; ++c)
                v[c] = Lg[0][b][i * 4 + c] + Lg[1][b][i * 4 + c];
            float m = fmaxf(fmaxf(v[0], v[1]), fmaxf(v[2], v[3]));
            m = fmaxf(m, __shfl_xor(m, 1));
            m = fmaxf(m, __shfl_xor(m, 2));
            m = fmaxf(m, __shfl_xor(m, 4));
            m = fmaxf(m, __shfl_xor(m, 8));
            float sum = expf(v[0] - m) + expf(v[1] - m) + expf(v[2] - m) + expf(v[3] - m);
            sum += __shfl_xor(sum, 1);
            sum += __shfl_xor(sum, 2);
            sum += __shfl_xor(sum, 4);
            sum += __shfl_xor(sum, 8);
            int tok = tokS[b][t];
            float sel = (i == (tok >> 2)) ? v[tok & 3] : 0.0f;
            sel += __shfl_xor(sel, 1);
            sel += __shfl_xor(sel, 2);
            sel += __shfl_xor(sel, 4);
            sel += __shfl_xor(sel, 8);
            llacc += sel - m - logf(sum);
        }
        LBAR;   // barrier2: new Xb8 visible, Lg consumed
    }

    if (w < 4 && (l & 15) == 0)
        out[b0 + w * 4 + (l >> 4)] = llacc;
}

extern "C" void kernel_launch(void* const* d_in, const int* in_sizes, int n_in,
                              void* d_out, int out_size, void* d_ws, size_t ws_size,
                              hipStream_t stream) {
    const float* A  = (const float*)d_in[0];   // (512,512)
    const float* B  = (const float*)d_in[1];   // (512,64)
    const float* C  = (const float*)d_in[2];   // (64,512)
    const float* Pp = (const float*)d_in[3];   // (64,512)
    const float* init = (const float*)d_in[4]; // (512,)
    const int* tokens = (const int*)d_in[5];   // (512,64)
    float* out = (float*)d_out;

    // workspace layout (needs 557,056 bytes)
    char*  A8  = (char*)d_ws;                                  // 512*512*1 = 262144
    char*  C8  = (char*)d_ws + 262144;                         // 64*512*1  =  32768
    f32x2* PPB = (f32x2*)((char*)d_ws + 294912);               // 64*512*8  = 262144

    ssm_prep<<<256, 256, 0, stream>>>(A, B, C, Pp, A8, C8, PPB);
    ssm_main<<<NWG, 512, 0, stream>>>(A8, C8, PPB, init, tokens, out);
}

// Round 23
// 164.626 us; speedup vs baseline: 1.5562x; 1.0789x over previous
//
#include <hip/hip_runtime.h>

#define K_DIM 512
#define S_DIM 64
#define T_LEN 64
#define BW    16      // sequences per workgroup
#define NWG   32      // 32 workgroups x 16 seqs = 512

typedef float f32x4 __attribute__((ext_vector_type(4)));
typedef float f32x2 __attribute__((ext_vector_type(2)));
typedef long  i64x2 __attribute__((ext_vector_type(2)));

__device__ __forceinline__ char f2fp8(float f) {   // OCP e4m3 on gfx950
    return (char)__builtin_amdgcn_cvt_pk_fp8_f32(f, f, 0, false);
}
// pack 4 floats -> 4 fp8 bytes (little-endian: a=byte0 .. d=byte3)
__device__ __forceinline__ unsigned pack4fp8(float a, float b, float c, float d) {
    unsigned v = __builtin_amdgcn_cvt_pk_fp8_f32(a, b, 0, false);
    v = __builtin_amdgcn_cvt_pk_fp8_f32(c, d, v, true);
    return v;
}

// ---------------- pre-pass: fp8 A + fp8 Ceff + packed {pi, pi*Bt} ----------------
__global__ void ssm_prep(const float* __restrict__ A, const float* __restrict__ B,
                         const float* __restrict__ C, const float* __restrict__ Pp,
                         char* __restrict__ A8, char* __restrict__ C8,
                         f32x2* __restrict__ PPB) {
    int i = blockIdx.x * blockDim.x + threadIdx.x;
    int stride = gridDim.x * blockDim.x;
    for (int idx = i; idx < K_DIM * K_DIM; idx += stride)
        A8[idx] = f2fp8(A[idx]);
    for (int idx = i; idx < S_DIM * K_DIM; idx += stride) {
        int s = idx >> 9;               // K_DIM == 512
        int k = idx & (K_DIM - 1);
        float p = 1.0f / (1.0f + expf(-Pp[idx]));
        C8[idx] = f2fp8(C[idx] * p);
        PPB[idx] = (f32x2){p, p * B[k * S_DIM + s]};   // {pi, pi*Bt[tok][k]}
    }
}

#define MFMA8(aj, bj, acc) acc = __builtin_amdgcn_mfma_f32_16x16x32_fp8_fp8(aj, bj, acc, 0, 0, 0)

// stream macro-slice m (K=64 chunk): 4 nt-rows x dwordx4 (16 fp8 = 2 k-slices)
#define LOADM(m) \
    i64x2 ga_##m = *(const i64x2*)(a8P0 + (m) * 64); \
    i64x2 gb_##m = *(const i64x2*)(a8P1 + (m) * 64); \
    i64x2 gc_##m = *(const i64x2*)(a8P2 + (m) * 64); \
    i64x2 gd_##m = *(const i64x2*)(a8P3 + (m) * 64);

// consume macro m: SWAPPED operand order (A-matrix = A-operand, x = B-operand)
// -> D[row=4lg+e -> k_out][col=lr -> seq]: thread owns seq=lr, 4 consecutive k
#define COMPM(m) { \
    i64x2 xv = *(const i64x2*)&Xb8[lr][(m) * 64 + 16 * lg]; \
    MFMA8(ga_##m[0], xv[0], acc0); MFMA8(ga_##m[1], xv[1], acc0); \
    MFMA8(gb_##m[0], xv[0], acc1); MFMA8(gb_##m[1], xv[1], acc1); \
    MFMA8(gc_##m[0], xv[0], acc2); MFMA8(gc_##m[1], xv[1], acc2); \
    MFMA8(gd_##m[0], xv[0], acc3); MFMA8(gd_##m[1], xv[1], acc3); }

// consume LDS-resident macro m (4..7), swapped order
#define COMPML(m) { \
    i64x2 xv = *(const i64x2*)&Xb8[lr][(m) * 64 + 16 * lg]; \
    i64x2 f0 = *(const i64x2*)&Aq8[w][(m) - 4][0][l][0]; \
    i64x2 f1 = *(const i64x2*)&Aq8[w][(m) - 4][1][l][0]; \
    i64x2 f2 = *(const i64x2*)&Aq8[w][(m) - 4][2][l][0]; \
    i64x2 f3 = *(const i64x2*)&Aq8[w][(m) - 4][3][l][0]; \
    MFMA8(f0[0], xv[0], acc0); MFMA8(f0[1], xv[1], acc0); \
    MFMA8(f1[0], xv[0], acc1); MFMA8(f1[1], xv[1], acc1); \
    MFMA8(f2[0], xv[0], acc2); MFMA8(f2[1], xv[1], acc2); \
    MFMA8(f3[0], xv[0], acc3); MFMA8(f3[1], xv[1], acc3); }

// raw barrier: drain LDS ops only; wave-private vmem loads ride across
#define LBAR asm volatile("s_waitcnt lgkmcnt(0)\ns_barrier" ::: "memory")

// ---------------- main: 32 WGs x 512 threads (8 waves), 16 seqs/WG, 64 steps ----------------
// R22 + T15-style deferred softmax: softmax(t-1) runs co-located with the
// COMPML MFMA cluster (separate VALU/MFMA pipes overlap within a wave, m114),
// instead of serializing between barrier1 and barrier2. Lg gains a parity dim
// (written Lg[p] in P1 of step t; read Lg[1-p] during step t+1, safe by the
// two intervening barriers). Numerically identical to R22.
__global__ __launch_bounds__(512) __attribute__((amdgpu_waves_per_eu(2, 2)))
void ssm_main(
    const char*  __restrict__ A8,      // [K][K] fp8 e4m3 row-major
    const char*  __restrict__ C8,      // [S][K] fp8 e4m3 (C * sigmoid(pi))
    const f32x2* __restrict__ PPB,     // [S][K] {pi, pi*Bt}
    const float* __restrict__ init,    // [K]
    const int*   __restrict__ tokens,  // [BSZ][T]
    float*       __restrict__ out)     // [BSZ]
{
    __shared__ char  Aq8[8][4][4][64][16];  // 128 KB: A cols 256..512 fp8, fragment order
    __shared__ char  Xb8[BW][528];          //  8.4 KB fp8 state (both GEMM paths)
    __shared__ float Lg[2][2][BW][68];      // 17.4 KB logits partials: parity x K-half
    __shared__ int   tokS[BW][T_LEN];       //  4.1 KB   (total 161,088 B -> 1 WG/CU)

    const int tid = threadIdx.x;
    const int w  = tid >> 6;     // wave 0..7, owns k-range [w*64, w*64+64)
    const int l  = tid & 63;
    const int lg = l >> 4;
    const int lr = l & 15;
    const int b0 = blockIdx.x * BW;

    for (int idx = tid; idx < BW * T_LEN; idx += 512) {
        int r = idx >> 6, t = idx & 63;
        tokS[r][t] = tokens[(b0 + r) * T_LEN + t];
    }
    for (int idx = tid; idx < BW * K_DIM; idx += 512) {
        int r = idx >> 9, k = idx & (K_DIM - 1);
        Xb8[r][k] = f2fp8(init[k]);
    }
    // stage A fp8 macros 4..7 into LDS in fragment order (once; reused 64 steps)
    for (int idx = tid; idx < 8192; idx += 512) {
        int w2 = idx >> 10, rem = idx & 1023;
        int m2 = rem >> 8, rem2 = rem & 255;
        int q2 = rem2 >> 6, l2 = rem2 & 63;
        *(i64x2*)&Aq8[w2][m2][q2][l2][0] =
            *(const i64x2*)(A8 + (w2 * 64 + q2 * 16 + (l2 & 15)) * K_DIM
                            + (4 + m2) * 64 + (l2 >> 4) * 16);
    }
    // fp32 master state: xm[nt][e] = x[seq=lr][k = w*64+nt*16+4*lg+e]
    float xm[4][4];
    #pragma unroll
    for (int nt = 0; nt < 4; ++nt) {
        #pragma unroll
        for (int e = 0; e < 4; ++e)
            xm[nt][e] = init[w * 64 + nt * 16 + 4 * lg + e];
    }

    const int sq = w & 3;    // logits s-tile
    const int kh = w >> 2;   // logits K-half

    // per-lane fp8 A bases (one per nt-quarter of the wave's 64 rows)
    const char* a8P0 = A8 + (w * 64 +      lr) * K_DIM + 16 * lg;
    const char* a8P1 = A8 + (w * 64 + 16 + lr) * K_DIM + 16 * lg;
    const char* a8P2 = A8 + (w * 64 + 32 + lr) * K_DIM + 16 * lg;
    const char* a8P3 = A8 + (w * 64 + 48 + lr) * K_DIM + 16 * lg;
    const char* c8P  = C8 + (sq * 16 + lr) * K_DIM + kh * 256 + 16 * lg;

    float llacc = 0.0f;
    __syncthreads();

    for (int t = 0; t < T_LEN; ++t) {
        const int p = t & 1;

        // ---- prime 2 macro-slices; latency hides under P1
        LOADM(0) LOADM(1)

        // ---- P1: logits partial GEMM (K-half kh), fp8, unswapped (x = A-op)
        f32x4 lga = {0.f, 0.f, 0.f, 0.f};
        #pragma unroll
        for (int j = 0; j < 4; ++j) {
            i64x2 cv = *(const i64x2*)(c8P + j * 64);
            i64x2 xv = *(const i64x2*)&Xb8[lr][kh * 256 + j * 64 + 16 * lg];
            MFMA8(xv[0], cv[0], lga);
            MFMA8(xv[1], cv[1], lga);
        }
        #pragma unroll
        for (int e = 0; e < 4; ++e)
            Lg[p][kh][4 * lg + e][sq * 16 + lr] = lga[e];

        // ---- P2: update GEMM fp8 (swapped), macros 0..3 streamed depth-2
        f32x4 acc0 = {0.f, 0.f, 0.f, 0.f};
        f32x4 acc1 = {0.f, 0.f, 0.f, 0.f};
        f32x4 acc2 = {0.f, 0.f, 0.f, 0.f};
        f32x4 acc3 = {0.f, 0.f, 0.f, 0.f};
        COMPM(0)  LOADM(2)
        COMPM(1)  LOADM(3)
        COMPM(2)
        COMPM(3)
        // ---- gating gathers: 1 token/thread, 8 contiguous f32x4 loads
        int mytok = tokS[lr][t];
        f32x4 ppv[4][2];   // ppv[nt][h]: {pi(e),pb(e),pi(e+1),pb(e+1)}, e=2h
        #pragma unroll
        for (int nt = 0; nt < 4; ++nt) {
            const f32x2* pp = PPB + mytok * K_DIM + w * 64 + nt * 16 + 4 * lg;
            ppv[nt][0] = *(const f32x4*)(pp);
            ppv[nt][1] = *(const f32x4*)(pp + 2);
        }

        // ---- deferred softmax for step t-1 (reads Lg[1-p], stable since the
        //      previous step's barriers). Pure VALU + LDS reads: overlaps with
        //      the 32 independent MFMAs of COMPML(4..7) below.
        if (t > 0 && w < 4) {
            int b = w * 4 + (l >> 4);
            int i = l & 15;
            float v[4];
            #pragma unroll
            for (int c = 0; c < 4; ++c)
                v[c] = Lg[1 - p][0][b][i * 4 + c] + Lg[1 - p][1][b][i * 4 + c];
            float m = fmaxf(fmaxf(v[0], v[1]), fmaxf(v[2], v[3]));
            m = fmaxf(m, __shfl_xor(m, 1));
            m = fmaxf(m, __shfl_xor(m, 2));
            m = fmaxf(m, __shfl_xor(m, 4));
            m = fmaxf(m, __shfl_xor(m, 8));
            float sum = expf(v[0] - m) + expf(v[1] - m) + expf(v[2] - m) + expf(v[3] - m);
            sum += __shfl_xor(sum, 1);
            sum += __shfl_xor(sum, 2);
            sum += __shfl_xor(sum, 4);
            sum += __shfl_xor(sum, 8);
            int tok = tokS[b][t - 1];
            float sel = (i == (tok >> 2)) ? v[tok & 3] : 0.0f;
            sel += __shfl_xor(sel, 1);
            sel += __shfl_xor(sel, 2);
            sel += __shfl_xor(sel, 4);
            sel += __shfl_xor(sel, 8);
            llacc += sel - m - logf(sum);
        }

        // ---- macros 4..7 from LDS (zero vmem)
        COMPML(4) COMPML(5) COMPML(6) COMPML(7)
        LBAR;   // barrier1: Xb8 reads done, Lg[p] visible

        // ---- P3: gating in fp32; thread owns seq=lr, 4 consecutive k per nt
        #pragma unroll
        for (int nt = 0; nt < 4; ++nt) {
            f32x4 a = (nt == 0) ? acc0 : (nt == 1) ? acc1 : (nt == 2) ? acc2 : acc3;
            float nx0 = xm[nt][0] + ppv[nt][0][0] * (a[0] - xm[nt][0]) + ppv[nt][0][1];
            float nx1 = xm[nt][1] + ppv[nt][0][2] * (a[1] - xm[nt][1]) + ppv[nt][0][3];
            float nx2 = xm[nt][2] + ppv[nt][1][0] * (a[2] - xm[nt][2]) + ppv[nt][1][1];
            float nx3 = xm[nt][3] + ppv[nt][1][2] * (a[3] - xm[nt][3]) + ppv[nt][1][3];
            xm[nt][0] = nx0; xm[nt][1] = nx1; xm[nt][2] = nx2; xm[nt][3] = nx3;
            *(unsigned*)&Xb8[lr][w * 64 + nt * 16 + 4 * lg] = pack4fp8(nx0, nx1, nx2, nx3);
        }
        LBAR;   // barrier2: new Xb8 visible, Lg[1-p] free for overwrite
    }

    // epilogue: softmax for the last step (t = 63, parity 1 -> Lg[1])
    if (w < 4) {
        int b = w * 4 + (l >> 4);
        int i = l & 15;
        float v[4];
        #pragma unroll
        for (int c = 0; c < 4; ++c)
            v[c] = Lg[1][0][b][i * 4 + c] + Lg[1][1][b][i * 4 + c];
        float m = fmaxf(fmaxf(v[0], v[1]), fmaxf(v[2], v[3]));
        m = fmaxf(m, __shfl_xor(m, 1));
        m = fmaxf(m, __shfl_xor(m, 2));
        m = fmaxf(m, __shfl_xor(m, 4));
        m = fmaxf(m, __shfl_xor(m, 8));
        float sum = expf(v[0] - m) + expf(v[1] - m) + expf(v[2] - m) + expf(v[3] - m);
        sum += __shfl_xor(sum, 1);
        sum += __shfl_xor(sum, 2);
        sum += __shfl_xor(sum, 4);
        sum += __shfl_xor(sum, 8);
        int tok = tokS[b][T_LEN - 1];
        float sel = (i == (tok >> 2)) ? v[tok & 3] : 0.0f;
        sel += __shfl_xor(sel, 1);
        sel += __shfl_xor(sel, 2);
        sel += __shfl_xor(sel, 4);
        sel += __shfl_xor(sel, 8);
        llacc += sel - m - logf(sum);

        if ((l & 15) == 0)
            out[b0 + w * 4 + (l >> 4)] = llacc;
    }
}

extern "C" void kernel_launch(void* const* d_in, const int* in_sizes, int n_in,
                              void* d_out, int out_size, void* d_ws, size_t ws_size,
                              hipStream_t stream) {
    const float* A  = (const float*)d_in[0];   // (512,512)
    const float* B  = (const float*)d_in[1];   // (512,64)
    const float* C  = (const float*)d_in[2];   // (64,512)
    const float* Pp = (const float*)d_in[3];   // (64,512)
    const float* init = (const float*)d_in[4]; // (512,)
    const int* tokens = (const int*)d_in[5];   // (512,64)
    float* out = (float*)d_out;

    // workspace layout (needs 557,056 bytes)
    char*  A8  = (char*)d_ws;                                  // 512*512*1 = 262144
    char*  C8  = (char*)d_ws + 262144;                         // 64*512*1  =  32768
    f32x2* PPB = (f32x2*)((char*)d_ws + 294912);               // 64*512*8  = 262144

    ssm_prep<<<256, 256, 0, stream>>>(A, B, C, Pp, A8, C8, PPB);
    ssm_main<<<NWG, 512, 0, stream>>>(A8, C8, PPB, init, tokens, out);
}

// Round 24
// 161.906 us; speedup vs baseline: 1.5823x; 1.0168x over previous
//
#include <hip/hip_runtime.h>

#define K_DIM 512
#define S_DIM 64
#define T_LEN 64
#define BW    16      // sequences per workgroup
#define NWG   32      // 32 workgroups x 16 seqs = 512

typedef float f32x4 __attribute__((ext_vector_type(4)));
typedef float f32x2 __attribute__((ext_vector_type(2)));
typedef long  i64x2 __attribute__((ext_vector_type(2)));

__device__ __forceinline__ char f2fp8(float f) {   // OCP e4m3 on gfx950
    return (char)__builtin_amdgcn_cvt_pk_fp8_f32(f, f, 0, false);
}
// pack 4 floats -> 4 fp8 bytes (little-endian: a=byte0 .. d=byte3)
__device__ __forceinline__ unsigned pack4fp8(float a, float b, float c, float d) {
    unsigned v = __builtin_amdgcn_cvt_pk_fp8_f32(a, b, 0, false);
    v = __builtin_amdgcn_cvt_pk_fp8_f32(c, d, v, true);
    return v;
}

// ---------------- pre-pass: fp8 A + fp8 Ceff + packed {pi, pi*Bt} ----------------
__global__ void ssm_prep(const float* __restrict__ A, const float* __restrict__ B,
                         const float* __restrict__ C, const float* __restrict__ Pp,
                         char* __restrict__ A8, char* __restrict__ C8,
                         f32x2* __restrict__ PPB) {
    int i = blockIdx.x * blockDim.x + threadIdx.x;
    int stride = gridDim.x * blockDim.x;
    for (int idx = i; idx < K_DIM * K_DIM; idx += stride)
        A8[idx] = f2fp8(A[idx]);
    for (int idx = i; idx < S_DIM * K_DIM; idx += stride) {
        int s = idx >> 9;               // K_DIM == 512
        int k = idx & (K_DIM - 1);
        float p = 1.0f / (1.0f + expf(-Pp[idx]));
        C8[idx] = f2fp8(C[idx] * p);
        PPB[idx] = (f32x2){p, p * B[k * S_DIM + s]};   // {pi, pi*Bt[tok][k]}
    }
}

#define MFMA8(aj, bj, acc) acc = __builtin_amdgcn_mfma_f32_16x16x32_fp8_fp8(aj, bj, acc, 0, 0, 0)

// stream macro-slice m (K=64 chunk): 4 nt-rows x dwordx4 (16 fp8 = 2 k-slices)
#define LOADM(m) \
    i64x2 ga_##m = *(const i64x2*)(a8P0 + (m) * 64); \
    i64x2 gb_##m = *(const i64x2*)(a8P1 + (m) * 64); \
    i64x2 gc_##m = *(const i64x2*)(a8P2 + (m) * 64); \
    i64x2 gd_##m = *(const i64x2*)(a8P3 + (m) * 64);

// consume macro m: SWAPPED operand order (A-matrix = A-operand, x = B-operand)
// -> D[row=4lg+e -> k_out][col=lr -> seq]: thread owns seq=lr, 4 consecutive k
#define COMPM(m) { \
    i64x2 xv = *(const i64x2*)&Xb8[lr][(m) * 64 + 16 * lg]; \
    MFMA8(ga_##m[0], xv[0], acc0); MFMA8(ga_##m[1], xv[1], acc0); \
    MFMA8(gb_##m[0], xv[0], acc1); MFMA8(gb_##m[1], xv[1], acc1); \
    MFMA8(gc_##m[0], xv[0], acc2); MFMA8(gc_##m[1], xv[1], acc2); \
    MFMA8(gd_##m[0], xv[0], acc3); MFMA8(gd_##m[1], xv[1], acc3); }

// consume LDS-resident macro m (4..6), swapped order
#define COMPML(m) { \
    i64x2 xv = *(const i64x2*)&Xb8[lr][(m) * 64 + 16 * lg]; \
    i64x2 f0 = *(const i64x2*)&Aq8[w][(m) - 4][0][l][0]; \
    i64x2 f1 = *(const i64x2*)&Aq8[w][(m) - 4][1][l][0]; \
    i64x2 f2 = *(const i64x2*)&Aq8[w][(m) - 4][2][l][0]; \
    i64x2 f3 = *(const i64x2*)&Aq8[w][(m) - 4][3][l][0]; \
    MFMA8(f0[0], xv[0], acc0); MFMA8(f0[1], xv[1], acc0); \
    MFMA8(f1[0], xv[0], acc1); MFMA8(f1[1], xv[1], acc1); \
    MFMA8(f2[0], xv[0], acc2); MFMA8(f2[1], xv[1], acc2); \
    MFMA8(f3[0], xv[0], acc3); MFMA8(f3[1], xv[1], acc3); }

// consume register-resident macro 7 (loop-invariant VGPRs, loaded once)
#define COMPR7() { \
    i64x2 xv = *(const i64x2*)&Xb8[lr][7 * 64 + 16 * lg]; \
    MFMA8(r7a[0], xv[0], acc0); MFMA8(r7a[1], xv[1], acc0); \
    MFMA8(r7b[0], xv[0], acc1); MFMA8(r7b[1], xv[1], acc1); \
    MFMA8(r7c[0], xv[0], acc2); MFMA8(r7c[1], xv[1], acc2); \
    MFMA8(r7d[0], xv[0], acc3); MFMA8(r7d[1], xv[1], acc3); }

// raw barrier: drain LDS ops only; wave-private vmem loads ride across
#define LBAR asm volatile("s_waitcnt lgkmcnt(0)\ns_barrier" ::: "memory")

// ---------------- main: 32 WGs x 512 threads (8 waves), 16 seqs/WG, 64 steps ----------------
// R23 + two LDS-pipe fixes (LDS is the dominant consumer: ~224 b128 wave-reads
// + 728 conflict-cy per CU-step): (1) tokS transposed [T][BW] -- old layout's
// dword addr lr*64+t put all 16 rows in ONE bank (16-way conflict on every P2
// token read); (2) macro 7 in 16 loop-INVARIANT VGPRs (loaded once; unlike
// R21's per-step CARRY there is no reload and no vmcnt interaction), cutting
// 4 of 28 per-wave ds_read_b128 and shrinking Aq8 to 3 macros (96 KB).
__global__ __launch_bounds__(512) __attribute__((amdgpu_waves_per_eu(2, 2)))
void ssm_main(
    const char*  __restrict__ A8,      // [K][K] fp8 e4m3 row-major
    const char*  __restrict__ C8,      // [S][K] fp8 e4m3 (C * sigmoid(pi))
    const f32x2* __restrict__ PPB,     // [S][K] {pi, pi*Bt}
    const float* __restrict__ init,    // [K]
    const int*   __restrict__ tokens,  // [BSZ][T]
    float*       __restrict__ out)     // [BSZ]
{
    __shared__ char  Aq8[8][3][4][64][16];  // 96 KB: A cols 256..448 fp8, fragment order
    __shared__ char  Xb8[BW][528];          //  8.4 KB fp8 state (both GEMM paths)
    __shared__ float Lg[2][2][BW][68];      // 17.4 KB logits partials: parity x K-half
    __shared__ int   tokS[T_LEN][BW];       //  4.1 KB TRANSPOSED (conflict-free reads)

    const int tid = threadIdx.x;
    const int w  = tid >> 6;     // wave 0..7, owns k-range [w*64, w*64+64)
    const int l  = tid & 63;
    const int lg = l >> 4;
    const int lr = l & 15;
    const int b0 = blockIdx.x * BW;

    for (int idx = tid; idx < BW * T_LEN; idx += 512) {
        int r = idx >> 6, t = idx & 63;
        tokS[t][r] = tokens[(b0 + r) * T_LEN + t];
    }
    for (int idx = tid; idx < BW * K_DIM; idx += 512) {
        int r = idx >> 9, k = idx & (K_DIM - 1);
        Xb8[r][k] = f2fp8(init[k]);
    }
    // stage A fp8 macros 4..6 into LDS in fragment order (once; reused 64 steps)
    for (int idx = tid; idx < 6144; idx += 512) {
        int w2 = idx / 768, rem = idx % 768;
        int m2 = rem >> 8, rem2 = rem & 255;
        int q2 = rem2 >> 6, l2 = rem2 & 63;
        *(i64x2*)&Aq8[w2][m2][q2][l2][0] =
            *(const i64x2*)(A8 + (w2 * 64 + q2 * 16 + (l2 & 15)) * K_DIM
                            + (4 + m2) * 64 + (l2 >> 4) * 16);
    }
    // fp32 master state: xm[nt][e] = x[seq=lr][k = w*64+nt*16+4*lg+e]
    float xm[4][4];
    #pragma unroll
    for (int nt = 0; nt < 4; ++nt) {
        #pragma unroll
        for (int e = 0; e < 4; ++e)
            xm[nt][e] = init[w * 64 + nt * 16 + 4 * lg + e];
    }

    const int sq = w & 3;    // logits s-tile
    const int kh = w >> 2;   // logits K-half

    // per-lane fp8 A bases (one per nt-quarter of the wave's 64 rows)
    const char* a8P0 = A8 + (w * 64 +      lr) * K_DIM + 16 * lg;
    const char* a8P1 = A8 + (w * 64 + 16 + lr) * K_DIM + 16 * lg;
    const char* a8P2 = A8 + (w * 64 + 32 + lr) * K_DIM + 16 * lg;
    const char* a8P3 = A8 + (w * 64 + 48 + lr) * K_DIM + 16 * lg;
    const char* c8P  = C8 + (sq * 16 + lr) * K_DIM + kh * 256 + 16 * lg;

    // macro 7 resident in loop-invariant VGPRs (16 regs, loaded ONCE)
    const i64x2 r7a = *(const i64x2*)(a8P0 + 7 * 64);
    const i64x2 r7b = *(const i64x2*)(a8P1 + 7 * 64);
    const i64x2 r7c = *(const i64x2*)(a8P2 + 7 * 64);
    const i64x2 r7d = *(const i64x2*)(a8P3 + 7 * 64);

    float llacc = 0.0f;
    __syncthreads();

    for (int t = 0; t < T_LEN; ++t) {
        const int p = t & 1;

        // ---- prime 2 macro-slices; latency hides under P1
        LOADM(0) LOADM(1)

        // ---- P1: logits partial GEMM (K-half kh), fp8, unswapped (x = A-op)
        f32x4 lga = {0.f, 0.f, 0.f, 0.f};
        #pragma unroll
        for (int j = 0; j < 4; ++j) {
            i64x2 cv = *(const i64x2*)(c8P + j * 64);
            i64x2 xv = *(const i64x2*)&Xb8[lr][kh * 256 + j * 64 + 16 * lg];
            MFMA8(xv[0], cv[0], lga);
            MFMA8(xv[1], cv[1], lga);
        }
        #pragma unroll
        for (int e = 0; e < 4; ++e)
            Lg[p][kh][4 * lg + e][sq * 16 + lr] = lga[e];

        // ---- P2: update GEMM fp8 (swapped), macros 0..3 streamed depth-2
        f32x4 acc0 = {0.f, 0.f, 0.f, 0.f};
        f32x4 acc1 = {0.f, 0.f, 0.f, 0.f};
        f32x4 acc2 = {0.f, 0.f, 0.f, 0.f};
        f32x4 acc3 = {0.f, 0.f, 0.f, 0.f};
        COMPM(0)  LOADM(2)
        COMPM(1)  LOADM(3)
        COMPM(2)
        COMPM(3)
        // ---- gating gathers: 1 token/thread, 8 contiguous f32x4 loads
        int mytok = tokS[t][lr];
        f32x4 ppv[4][2];   // ppv[nt][h]: {pi(e),pb(e),pi(e+1),pb(e+1)}, e=2h
        #pragma unroll
        for (int nt = 0; nt < 4; ++nt) {
            const f32x2* pp = PPB + mytok * K_DIM + w * 64 + nt * 16 + 4 * lg;
            ppv[nt][0] = *(const f32x4*)(pp);
            ppv[nt][1] = *(const f32x4*)(pp + 2);
        }

        // ---- deferred softmax for step t-1 (reads Lg[1-p], stable since the
        //      previous step's barriers); overlaps with COMPML/COMPR7 MFMAs
        if (t > 0 && w < 4) {
            int b = w * 4 + (l >> 4);
            int i = l & 15;
            float v[4];
            #pragma unroll
            for (int c = 0; c < 4; ++c)
                v[c] = Lg[1 - p][0][b][i * 4 + c] + Lg[1 - p][1][b][i * 4 + c];
            float m = fmaxf(fmaxf(v[0], v[1]), fmaxf(v[2], v[3]));
            m = fmaxf(m, __shfl_xor(m, 1));
            m = fmaxf(m, __shfl_xor(m, 2));
            m = fmaxf(m, __shfl_xor(m, 4));
            m = fmaxf(m, __shfl_xor(m, 8));
            float sum = expf(v[0] - m) + expf(v[1] - m) + expf(v[2] - m) + expf(v[3] - m);
            sum += __shfl_xor(sum, 1);
            sum += __shfl_xor(sum, 2);
            sum += __shfl_xor(sum, 4);
            sum += __shfl_xor(sum, 8);
            int tok = tokS[t - 1][b];
            float sel = (i == (tok >> 2)) ? v[tok & 3] : 0.0f;
            sel += __shfl_xor(sel, 1);
            sel += __shfl_xor(sel, 2);
            sel += __shfl_xor(sel, 4);
            sel += __shfl_xor(sel, 8);
            llacc += sel - m - logf(sum);
        }

        // ---- macros 4..6 from LDS, macro 7 from registers
        COMPML(4) COMPML(5) COMPML(6) COMPR7()
        LBAR;   // barrier1: Xb8 reads done, Lg[p] visible

        // ---- P3: gating in fp32; thread owns seq=lr, 4 consecutive k per nt
        #pragma unroll
        for (int nt = 0; nt < 4; ++nt) {
            f32x4 a = (nt == 0) ? acc0 : (nt == 1) ? acc1 : (nt == 2) ? acc2 : acc3;
            float nx0 = xm[nt][0] + ppv[nt][0][0] * (a[0] - xm[nt][0]) + ppv[nt][0][1];
            float nx1 = xm[nt][1] + ppv[nt][0][2] * (a[1] - xm[nt][1]) + ppv[nt][0][3];
            float nx2 = xm[nt][2] + ppv[nt][1][0] * (a[2] - xm[nt][2]) + ppv[nt][1][1];
            float nx3 = xm[nt][3] + ppv[nt][1][2] * (a[3] - xm[nt][3]) + ppv[nt][1][3];
            xm[nt][0] = nx0; xm[nt][1] = nx1; xm[nt][2] = nx2; xm[nt][3] = nx3;
            *(unsigned*)&Xb8[lr][w * 64 + nt * 16 + 4 * lg] = pack4fp8(nx0, nx1, nx2, nx3);
        }
        LBAR;   // barrier2: new Xb8 visible, Lg[1-p] free for overwrite
    }

    // epilogue: softmax for the last step (t = 63, parity 1 -> Lg[1])
    if (w < 4) {
        int b = w * 4 + (l >> 4);
        int i = l & 15;
        float v[4];
        #pragma unroll
        for (int c = 0; c < 4; ++c)
            v[c] = Lg[1][0][b][i * 4 + c] + Lg[1][1][b][i * 4 + c];
        float m = fmaxf(fmaxf(v[0], v[1]), fmaxf(v[2], v[3]));
        m = fmaxf(m, __shfl_xor(m, 1));
        m = fmaxf(m, __shfl_xor(m, 2));
        m = fmaxf(m, __shfl_xor(m, 4));
        m = fmaxf(m, __shfl_xor(m, 8));
        float sum = expf(v[0] - m) + expf(v[1] - m) + expf(v[2] - m) + expf(v[3] - m);
        sum += __shfl_xor(sum, 1);
        sum += __shfl_xor(sum, 2);
        sum += __shfl_xor(sum, 4);
        sum += __shfl_xor(sum, 8);
        int tok = tokS[T_LEN - 1][b];
        float sel = (i == (tok >> 2)) ? v[tok & 3] : 0.0f;
        sel += __shfl_xor(sel, 1);
        sel += __shfl_xor(sel, 2);
        sel += __shfl_xor(sel, 4);
        sel += __shfl_xor(sel, 8);
        llacc += sel - m - logf(sum);

        if ((l & 15) == 0)
            out[b0 + w * 4 + (l >> 4)] = llacc;
    }
}

extern "C" void kernel_launch(void* const* d_in, const int* in_sizes, int n_in,
                              void* d_out, int out_size, void* d_ws, size_t ws_size,
                              hipStream_t stream) {
    const float* A  = (const float*)d_in[0];   // (512,512)
    const float* B  = (const float*)d_in[1];   // (512,64)
    const float* C  = (const float*)d_in[2];   // (64,512)
    const float* Pp = (const float*)d_in[3];   // (64,512)
    const float* init = (const float*)d_in[4]; // (512,)
    const int* tokens = (const int*)d_in[5];   // (512,64)
    float* out = (float*)d_out;

    // workspace layout (needs 557,056 bytes)
    char*  A8  = (char*)d_ws;                                  // 512*512*1 = 262144
    char*  C8  = (char*)d_ws + 262144;                         // 64*512*1  =  32768
    f32x2* PPB = (f32x2*)((char*)d_ws + 294912);               // 64*512*8  = 262144

    ssm_prep<<<256, 256, 0, stream>>>(A, B, C, Pp, A8, C8, PPB);
    ssm_main<<<NWG, 512, 0, stream>>>(A8, C8, PPB, init, tokens, out);
}

// Round 25
// 160.283 us; speedup vs baseline: 1.5983x; 1.0101x over previous
//
#include <hip/hip_runtime.h>

#define K_DIM 512
#define S_DIM 64
#define T_LEN 64
#define BW    16      // sequences per workgroup
#define NWG   32      // 32 workgroups x 16 seqs = 512

typedef float f32x4 __attribute__((ext_vector_type(4)));
typedef float f32x2 __attribute__((ext_vector_type(2)));
typedef long  i64x2 __attribute__((ext_vector_type(2)));

__device__ __forceinline__ char f2fp8(float f) {   // OCP e4m3 on gfx950
    return (char)__builtin_amdgcn_cvt_pk_fp8_f32(f, f, 0, false);
}
// pack 4 floats -> 4 fp8 bytes (little-endian: a=byte0 .. d=byte3)
__device__ __forceinline__ unsigned pack4fp8(float a, float b, float c, float d) {
    unsigned v = __builtin_amdgcn_cvt_pk_fp8_f32(a, b, 0, false);
    v = __builtin_amdgcn_cvt_pk_fp8_f32(c, d, v, true);
    return v;
}

// ---------------- pre-pass: fp8 A + fp8 Ceff + packed {pi, pi*Bt} ----------------
__global__ void ssm_prep(const float* __restrict__ A, const float* __restrict__ B,
                         const float* __restrict__ C, const float* __restrict__ Pp,
                         char* __restrict__ A8, char* __restrict__ C8,
                         f32x2* __restrict__ PPB) {
    int i = blockIdx.x * blockDim.x + threadIdx.x;
    int stride = gridDim.x * blockDim.x;
    for (int idx = i; idx < K_DIM * K_DIM; idx += stride)
        A8[idx] = f2fp8(A[idx]);
    for (int idx = i; idx < S_DIM * K_DIM; idx += stride) {
        int s = idx >> 9;               // K_DIM == 512
        int k = idx & (K_DIM - 1);
        float p = 1.0f / (1.0f + expf(-Pp[idx]));
        C8[idx] = f2fp8(C[idx] * p);
        PPB[idx] = (f32x2){p, p * B[k * S_DIM + s]};   // {pi, pi*Bt[tok][k]}
    }
}

#define MFMA8(aj, bj, acc) acc = __builtin_amdgcn_mfma_f32_16x16x32_fp8_fp8(aj, bj, acc, 0, 0, 0)

// stream macro-slice m (K=64 chunk): 4 nt-rows x dwordx4 (16 fp8 = 2 k-slices)
#define LOADM(m) \
    i64x2 ga_##m = *(const i64x2*)(a8P0 + (m) * 64); \
    i64x2 gb_##m = *(const i64x2*)(a8P1 + (m) * 64); \
    i64x2 gc_##m = *(const i64x2*)(a8P2 + (m) * 64); \
    i64x2 gd_##m = *(const i64x2*)(a8P3 + (m) * 64);

// consume macro m: SWAPPED operand order (A-matrix = A-operand, x = B-operand)
// -> D[row=4lg+e -> k_out][col=lr -> seq]: thread owns seq=lr, 4 consecutive k
#define COMPM(m) { \
    i64x2 xv = *(const i64x2*)&Xb8[lr][(m) * 64 + 16 * lg]; \
    MFMA8(ga_##m[0], xv[0], acc0); MFMA8(ga_##m[1], xv[1], acc0); \
    MFMA8(gb_##m[0], xv[0], acc1); MFMA8(gb_##m[1], xv[1], acc1); \
    MFMA8(gc_##m[0], xv[0], acc2); MFMA8(gc_##m[1], xv[1], acc2); \
    MFMA8(gd_##m[0], xv[0], acc3); MFMA8(gd_##m[1], xv[1], acc3); }

// consume LDS-resident macro m (4..5), swapped order
#define COMPML(m) { \
    i64x2 xv = *(const i64x2*)&Xb8[lr][(m) * 64 + 16 * lg]; \
    i64x2 f0 = *(const i64x2*)&Aq8[w][(m) - 4][0][l][0]; \
    i64x2 f1 = *(const i64x2*)&Aq8[w][(m) - 4][1][l][0]; \
    i64x2 f2 = *(const i64x2*)&Aq8[w][(m) - 4][2][l][0]; \
    i64x2 f3 = *(const i64x2*)&Aq8[w][(m) - 4][3][l][0]; \
    MFMA8(f0[0], xv[0], acc0); MFMA8(f0[1], xv[1], acc0); \
    MFMA8(f1[0], xv[0], acc1); MFMA8(f1[1], xv[1], acc1); \
    MFMA8(f2[0], xv[0], acc2); MFMA8(f2[1], xv[1], acc2); \
    MFMA8(f3[0], xv[0], acc3); MFMA8(f3[1], xv[1], acc3); }

// consume register-resident macros 6,7 (loop-invariant VGPRs, loaded once)
#define COMPR(m, ra, rb, rc, rd) { \
    i64x2 xv = *(const i64x2*)&Xb8[lr][(m) * 64 + 16 * lg]; \
    MFMA8(ra[0], xv[0], acc0); MFMA8(ra[1], xv[1], acc0); \
    MFMA8(rb[0], xv[0], acc1); MFMA8(rb[1], xv[1], acc1); \
    MFMA8(rc[0], xv[0], acc2); MFMA8(rc[1], xv[1], acc2); \
    MFMA8(rd[0], xv[0], acc3); MFMA8(rd[1], xv[1], acc3); }

// raw barrier: drain LDS ops only; wave-private vmem loads ride across
#define LBAR asm volatile("s_waitcnt lgkmcnt(0)\ns_barrier" ::: "memory")

// ---------------- main: 32 WGs x 512 threads (8 waves), 16 seqs/WG, 64 steps ----------------
// R24 + (1) macro 6 ALSO in loop-invariant VGPRs (mirror of the proven macro-7
// move; R24 showed zero VGPR growth): per-wave ds_read_b128 24 -> 20/step,
// Aq8 -> 2 macros (64 KB); (2) softmax Lg reads as 2x f32x4 (16B-aligned,
// minimum-aliased -> conflict-free) instead of 8x b32 at 8-way conflict.
__global__ __launch_bounds__(512) __attribute__((amdgpu_waves_per_eu(2, 2)))
void ssm_main(
    const char*  __restrict__ A8,      // [K][K] fp8 e4m3 row-major
    const char*  __restrict__ C8,      // [S][K] fp8 e4m3 (C * sigmoid(pi))
    const f32x2* __restrict__ PPB,     // [S][K] {pi, pi*Bt}
    const float* __restrict__ init,    // [K]
    const int*   __restrict__ tokens,  // [BSZ][T]
    float*       __restrict__ out)     // [BSZ]
{
    __shared__ char  Aq8[8][2][4][64][16];  // 64 KB: A cols 256..384 fp8, fragment order
    __shared__ char  Xb8[BW][528];          //  8.4 KB fp8 state (both GEMM paths)
    __shared__ float Lg[2][2][BW][68];      // 17.4 KB logits partials: parity x K-half
    __shared__ int   tokS[T_LEN][BW];       //  4.1 KB transposed (conflict-free reads)

    const int tid = threadIdx.x;
    const int w  = tid >> 6;     // wave 0..7, owns k-range [w*64, w*64+64)
    const int l  = tid & 63;
    const int lg = l >> 4;
    const int lr = l & 15;
    const int b0 = blockIdx.x * BW;

    for (int idx = tid; idx < BW * T_LEN; idx += 512) {
        int r = idx >> 6, t = idx & 63;
        tokS[t][r] = tokens[(b0 + r) * T_LEN + t];
    }
    for (int idx = tid; idx < BW * K_DIM; idx += 512) {
        int r = idx >> 9, k = idx & (K_DIM - 1);
        Xb8[r][k] = f2fp8(init[k]);
    }
    // stage A fp8 macros 4..5 into LDS in fragment order (once; reused 64 steps)
    for (int idx = tid; idx < 4096; idx += 512) {
        int w2 = idx >> 9, rem = idx & 511;
        int m2 = rem >> 8, rem2 = rem & 255;
        int q2 = rem2 >> 6, l2 = rem2 & 63;
        *(i64x2*)&Aq8[w2][m2][q2][l2][0] =
            *(const i64x2*)(A8 + (w2 * 64 + q2 * 16 + (l2 & 15)) * K_DIM
                            + (4 + m2) * 64 + (l2 >> 4) * 16);
    }
    // fp32 master state: xm[nt][e] = x[seq=lr][k = w*64+nt*16+4*lg+e]
    float xm[4][4];
    #pragma unroll
    for (int nt = 0; nt < 4; ++nt) {
        #pragma unroll
        for (int e = 0; e < 4; ++e)
            xm[nt][e] = init[w * 64 + nt * 16 + 4 * lg + e];
    }

    const int sq = w & 3;    // logits s-tile
    const int kh = w >> 2;   // logits K-half

    // per-lane fp8 A bases (one per nt-quarter of the wave's 64 rows)
    const char* a8P0 = A8 + (w * 64 +      lr) * K_DIM + 16 * lg;
    const char* a8P1 = A8 + (w * 64 + 16 + lr) * K_DIM + 16 * lg;
    const char* a8P2 = A8 + (w * 64 + 32 + lr) * K_DIM + 16 * lg;
    const char* a8P3 = A8 + (w * 64 + 48 + lr) * K_DIM + 16 * lg;
    const char* c8P  = C8 + (sq * 16 + lr) * K_DIM + kh * 256 + 16 * lg;

    // macros 6,7 resident in loop-invariant VGPRs (32 regs, loaded ONCE)
    const i64x2 r6a = *(const i64x2*)(a8P0 + 6 * 64);
    const i64x2 r6b = *(const i64x2*)(a8P1 + 6 * 64);
    const i64x2 r6c = *(const i64x2*)(a8P2 + 6 * 64);
    const i64x2 r6d = *(const i64x2*)(a8P3 + 6 * 64);
    const i64x2 r7a = *(const i64x2*)(a8P0 + 7 * 64);
    const i64x2 r7b = *(const i64x2*)(a8P1 + 7 * 64);
    const i64x2 r7c = *(const i64x2*)(a8P2 + 7 * 64);
    const i64x2 r7d = *(const i64x2*)(a8P3 + 7 * 64);

    float llacc = 0.0f;
    __syncthreads();

    for (int t = 0; t < T_LEN; ++t) {
        const int p = t & 1;

        // ---- prime 2 macro-slices; latency hides under P1
        LOADM(0) LOADM(1)

        // ---- P1: logits partial GEMM (K-half kh), fp8, unswapped (x = A-op)
        f32x4 lga = {0.f, 0.f, 0.f, 0.f};
        #pragma unroll
        for (int j = 0; j < 4; ++j) {
            i64x2 cv = *(const i64x2*)(c8P + j * 64);
            i64x2 xv = *(const i64x2*)&Xb8[lr][kh * 256 + j * 64 + 16 * lg];
            MFMA8(xv[0], cv[0], lga);
            MFMA8(xv[1], cv[1], lga);
        }
        #pragma unroll
        for (int e = 0; e < 4; ++e)
            Lg[p][kh][4 * lg + e][sq * 16 + lr] = lga[e];

        // ---- P2: update GEMM fp8 (swapped), macros 0..3 streamed depth-2
        f32x4 acc0 = {0.f, 0.f, 0.f, 0.f};
        f32x4 acc1 = {0.f, 0.f, 0.f, 0.f};
        f32x4 acc2 = {0.f, 0.f, 0.f, 0.f};
        f32x4 acc3 = {0.f, 0.f, 0.f, 0.f};
        COMPM(0)  LOADM(2)
        COMPM(1)  LOADM(3)
        COMPM(2)
        COMPM(3)
        // ---- gating gathers: 1 token/thread, 8 contiguous f32x4 loads
        int mytok = tokS[t][lr];
        f32x4 ppv[4][2];   // ppv[nt][h]: {pi(e),pb(e),pi(e+1),pb(e+1)}, e=2h
        #pragma unroll
        for (int nt = 0; nt < 4; ++nt) {
            const f32x2* pp = PPB + mytok * K_DIM + w * 64 + nt * 16 + 4 * lg;
            ppv[nt][0] = *(const f32x4*)(pp);
            ppv[nt][1] = *(const f32x4*)(pp + 2);
        }

        // ---- deferred softmax for step t-1 (reads Lg[1-p] via 2x b128,
        //      conflict-free); overlaps with COMPML/COMPR MFMAs below
        if (t > 0 && w < 4) {
            int b = w * 4 + (l >> 4);
            int i = l & 15;
            f32x4 v0 = *(const f32x4*)&Lg[1 - p][0][b][i * 4];
            f32x4 v1 = *(const f32x4*)&Lg[1 - p][1][b][i * 4];
            float v[4];
            #pragma unroll
            for (int c = 0; c < 4; ++c) v[c] = v0[c] + v1[c];
            float m = fmaxf(fmaxf(v[0], v[1]), fmaxf(v[2], v[3]));
            m = fmaxf(m, __shfl_xor(m, 1));
            m = fmaxf(m, __shfl_xor(m, 2));
            m = fmaxf(m, __shfl_xor(m, 4));
            m = fmaxf(m, __shfl_xor(m, 8));
            float sum = expf(v[0] - m) + expf(v[1] - m) + expf(v[2] - m) + expf(v[3] - m);
            sum += __shfl_xor(sum, 1);
            sum += __shfl_xor(sum, 2);
            sum += __shfl_xor(sum, 4);
            sum += __shfl_xor(sum, 8);
            int tok = tokS[t - 1][b];
            float sel = (i == (tok >> 2)) ? v[tok & 3] : 0.0f;
            sel += __shfl_xor(sel, 1);
            sel += __shfl_xor(sel, 2);
            sel += __shfl_xor(sel, 4);
            sel += __shfl_xor(sel, 8);
            llacc += sel - m - logf(sum);
        }

        // ---- macros 4..5 from LDS, macros 6,7 from registers
        COMPML(4) COMPML(5)
        COMPR(6, r6a, r6b, r6c, r6d)
        COMPR(7, r7a, r7b, r7c, r7d)
        LBAR;   // barrier1: Xb8 reads done, Lg[p] visible

        // ---- P3: gating in fp32; thread owns seq=lr, 4 consecutive k per nt
        #pragma unroll
        for (int nt = 0; nt < 4; ++nt) {
            f32x4 a = (nt == 0) ? acc0 : (nt == 1) ? acc1 : (nt == 2) ? acc2 : acc3;
            float nx0 = xm[nt][0] + ppv[nt][0][0] * (a[0] - xm[nt][0]) + ppv[nt][0][1];
            float nx1 = xm[nt][1] + ppv[nt][0][2] * (a[1] - xm[nt][1]) + ppv[nt][0][3];
            float nx2 = xm[nt][2] + ppv[nt][1][0] * (a[2] - xm[nt][2]) + ppv[nt][1][1];
            float nx3 = xm[nt][3] + ppv[nt][1][2] * (a[3] - xm[nt][3]) + ppv[nt][1][3];
            xm[nt][0] = nx0; xm[nt][1] = nx1; xm[nt][2] = nx2; xm[nt][3] = nx3;
            *(unsigned*)&Xb8[lr][w * 64 + nt * 16 + 4 * lg] = pack4fp8(nx0, nx1, nx2, nx3);
        }
        LBAR;   // barrier2: new Xb8 visible, Lg[1-p] free for overwrite
    }

    // epilogue: softmax for the last step (t = 63, parity 1 -> Lg[1])
    if (w < 4) {
        int b = w * 4 + (l >> 4);
        int i = l & 15;
        f32x4 v0 = *(const f32x4*)&Lg[1][0][b][i * 4];
        f32x4 v1 = *(const f32x4*)&Lg[1][1][b][i * 4];
        float v[4];
        #pragma unroll
        for (int c = 0; c < 4; ++c) v[c] = v0[c] + v1[c];
        float m = fmaxf(fmaxf(v[0], v[1]), fmaxf(v[2], v[3]));
        m = fmaxf(m, __shfl_xor(m, 1));
        m = fmaxf(m, __shfl_xor(m, 2));
        m = fmaxf(m, __shfl_xor(m, 4));
        m = fmaxf(m, __shfl_xor(m, 8));
        float sum = expf(v[0] - m) + expf(v[1] - m) + expf(v[2] - m) + expf(v[3] - m);
        sum += __shfl_xor(sum, 1);
        sum += __shfl_xor(sum, 2);
        sum += __shfl_xor(sum, 4);
        sum += __shfl_xor(sum, 8);
        int tok = tokS[T_LEN - 1][b];
        float sel = (i == (tok >> 2)) ? v[tok & 3] : 0.0f;
        sel += __shfl_xor(sel, 1);
        sel += __shfl_xor(sel, 2);
        sel += __shfl_xor(sel, 4);
        sel += __shfl_xor(sel, 8);
        llacc += sel - m - logf(sum);

        if ((l & 15) == 0)
            out[b0 + w * 4 + (l >> 4)] = llacc;
    }
}

extern "C" void kernel_launch(void* const* d_in, const int* in_sizes, int n_in,
                              void* d_out, int out_size, void* d_ws, size_t ws_size,
                              hipStream_t stream) {
    const float* A  = (const float*)d_in[0];   // (512,512)
    const float* B  = (const float*)d_in[1];   // (512,64)
    const float* C  = (const float*)d_in[2];   // (64,512)
    const float* Pp = (const float*)d_in[3];   // (64,512)
    const float* init = (const float*)d_in[4]; // (512,)
    const int* tokens = (const int*)d_in[5];   // (512,64)
    float* out = (float*)d_out;

    // workspace layout (needs 557,056 bytes)
    char*  A8  = (char*)d_ws;                                  // 512*512*1 = 262144
    char*  C8  = (char*)d_ws + 262144;                         // 64*512*1  =  32768
    f32x2* PPB = (f32x2*)((char*)d_ws + 294912);               // 64*512*8  = 262144

    ssm_prep<<<256, 256, 0, stream>>>(A, B, C, Pp, A8, C8, PPB);
    ssm_main<<<NWG, 512, 0, stream>>>(A8, C8, PPB, init, tokens, out);
}